// Round 19
// baseline (228.624 us; speedup 1.0000x reference)
//
#include <hip/hip_runtime.h>
#include <hip/hip_fp16.h>
#include <math.h>

#define NN 100000
#define NE 1600000
#define D 128
#define DOUT 40
#define NBUCK 391          // ceil(NN/256): bucket = 256 consecutive nodes
#define CHUNK 4096         // edges per binning workgroup (fat chunks amortize per-block NBUCK scan)
#define NCHUNK 391         // ceil(NE/CHUNK)
#define NCHP 392           // padded partial-histogram stride (98 uint4)
#define EPT 16             // CHUNK/256 edges per thread
#define LSTR 136           // LDS row stride in f16: 272B = 17*16B (aligned)
#define BCAP 5120          // bucket_build LDS edge cache capacity

typedef _Float16 half8v __attribute__((ext_vector_type(8)));   // 8 f16 (4 VGPR)
typedef __attribute__((ext_vector_type(4))) float f32x4;

__device__ __forceinline__ unsigned packh(float a, float b) {
  return (unsigned)__half_as_ushort(__float2half_rn(a)) |
         ((unsigned)__half_as_ushort(__float2half_rn(b)) << 16);
}
// fp8 e4m3 (OCP) helpers — HW converts on gfx950
__device__ __forceinline__ unsigned char f2fp8(float v) {
  return (unsigned char)(__builtin_amdgcn_cvt_pk_fp8_f32(v, v, 0, 0) & 0xff);
}
#define CVT2(u, s) __builtin_amdgcn_cvt_pk_f32_fp8((int)(u), s)
// accumulate 16 fp8 (one uint4) into a[0..15]
#define ACCR(v) { auto q = CVT2((v).x, 0); a[0] += q[0]; a[1] += q[1];   \
  q = CVT2((v).x, 1); a[2] += q[0];  a[3] += q[1];                        \
  q = CVT2((v).y, 0); a[4] += q[0];  a[5] += q[1];                        \
  q = CVT2((v).y, 1); a[6] += q[0];  a[7] += q[1];                        \
  q = CVT2((v).z, 0); a[8] += q[0];  a[9] += q[1];                        \
  q = CVT2((v).z, 1); a[10] += q[0]; a[11] += q[1];                       \
  q = CVT2((v).w, 0); a[12] += q[0]; a[13] += q[1];                       \
  q = CVT2((v).w, 1); a[14] += q[0]; a[15] += q[1]; }
// accumulate 8 fp8 (one uint2) into a[0..7]
#define ACCR8(v) { auto q = CVT2((v).x, 0); a[0] += q[0]; a[1] += q[1];  \
  q = CVT2((v).x, 1); a[2] += q[0]; a[3] += q[1];                         \
  q = CVT2((v).y, 0); a[4] += q[0]; a[5] += q[1];                         \
  q = CVT2((v).y, 1); a[6] += q[0]; a[7] += q[1]; }

// 8 fp8 (uint2) -> half8v via HW fp8->f32
__device__ __forceinline__ half8v fp8_to_h8(uint2 u) {
  auto q0 = CVT2(u.x, 0);
  auto q1 = CVT2(u.x, 1);
  auto q2 = CVT2(u.y, 0);
  auto q3 = CVT2(u.y, 1);
  half8v h;
  h[0] = (_Float16)q0[0]; h[1] = (_Float16)q0[1];
  h[2] = (_Float16)q1[0]; h[3] = (_Float16)q1[1];
  h[4] = (_Float16)q2[0]; h[5] = (_Float16)q2[1];
  h[6] = (_Float16)q3[0]; h[7] = (_Float16)q3[1];
  return h;
}

// ---------------- fused prep: x->f16+fp8, weight planes, per-chunk bucket histograms ----------------
// blocks: [0,6250) cvt | [6250,6266) B0 | [6266,6282) B1 | [6282,6287) By2 | [6287,6678) hist
__global__ __launch_bounds__(256) void prep_all_kernel(
    const float* __restrict__ x, _Float16* __restrict__ xb, unsigned char* __restrict__ x8,
    const float* __restrict__ Wl0, const float* __restrict__ Wr0, half8v* __restrict__ B0,
    const float* __restrict__ Wl1, const float* __restrict__ Wr1, half8v* __restrict__ B1,
    const float* __restrict__ Wl2, const float* __restrict__ Wr2, half8v* __restrict__ By2,
    const int* __restrict__ dst, int* __restrict__ partial) {
  int bid = blockIdx.x;
  int t = threadIdx.x;
  if (bid < 6250) {  // cvt
    int i = (bid * 256 + t) * 8;
    float4 v0 = *(const float4*)(x + i);
    float4 v1 = *(const float4*)(x + i + 4);
    uint4 oh;
    oh.x = packh(v0.x, v0.y);
    oh.y = packh(v0.z, v0.w);
    oh.z = packh(v1.x, v1.y);
    oh.w = packh(v1.z, v1.w);
    *(uint4*)(xb + i) = oh;
    unsigned w0 = __builtin_amdgcn_cvt_pk_fp8_f32(v0.x, v0.y, 0, 0);
    w0 = __builtin_amdgcn_cvt_pk_fp8_f32(v0.z, v0.w, w0, 1);
    unsigned w1 = __builtin_amdgcn_cvt_pk_fp8_f32(v1.x, v1.y, 0, 0);
    w1 = __builtin_amdgcn_cvt_pk_fp8_f32(v1.z, v1.w, w1, 1);
    *(uint2*)(x8 + i) = make_uint2(w0, w1);
  } else if (bid < 6282) {  // B0 / B1 planes
    const float* Wl = (bid < 6266) ? Wl0 : Wl1;
    const float* Wr = (bid < 6266) ? Wr0 : Wr1;
    half8v* P = (bid < 6266) ? B0 : B1;
    int rel = (bid < 6266) ? bid - 6250 : bid - 6266;
    int ob = rel * 4 + (t >> 6);  // 0..63
    int l = t & 63;
    int s = ob >> 3, n = ob & 7;
    int k0 = s * 32 + (l >> 4) * 8;
    int c = n * 16 + (l & 15);
    const float* W = (k0 < 128) ? Wl : Wr;
    int kb = (k0 < 128) ? k0 : k0 - 128;
    half8v h;
#pragma unroll
    for (int i = 0; i < 8; ++i) h[i] = (_Float16)W[c * 128 + kb + i];
    P[ob * 64 + l] = h;
  } else if (bid < 6287) {  // By2 plane: cols 0..39 = Wl2 rows, 40..79 = Wr2 rows
    int rel = bid - 6282;
    int ob = rel * 4 + (t >> 6);  // 0..19
    int l = t & 63;
    int s = ob / 5, n = ob % 5;
    int k0 = s * 32 + (l >> 4) * 8;
    int c = n * 16 + (l & 15);
    const float* W = (c < DOUT) ? Wl2 : Wr2;
    int row = (c < DOUT) ? c : c - DOUT;
    half8v h;
#pragma unroll
    for (int i = 0; i < 8; ++i) h[i] = (_Float16)W[row * 128 + k0 + i];
    By2[ob * 64 + l] = h;
  } else {  // hist chunk c: LDS histogram, write column c of partial[b][c]
    __shared__ int bc[NBUCK];
    int c = bid - 6287;
    for (int i = t; i < NBUCK; i += 256) bc[i] = 0;
    __syncthreads();
    int e_base = c * CHUNK;
#pragma unroll
    for (int j = 0; j < EPT; ++j) {
      int e = e_base + j * 256 + t;
      if (e < NE) atomicAdd(&bc[dst[e] >> 8], 1);
    }
    __syncthreads();
    for (int i = t; i < NBUCK; i += 256) partial[i * NCHP + c] = bc[i];
    if (c == 0)
      for (int i = t; i < NBUCK; i += 256) partial[i * NCHP + NCHP - 1] = 0;  // pad col
  }
}

// ---------------- bucket scan: reduce partials + exclusive scan ----------------
__global__ __launch_bounds__(512) void bucket_scan_kernel(const int* __restrict__ partial,
                                                          int* __restrict__ bucket_base,
                                                          int* __restrict__ bucket_cursor) {
  __shared__ int s[512];
  int t = threadIdx.x;
  int c = 0;
  if (t < NBUCK) {
    const uint4* row = (const uint4*)(partial + t * NCHP);  // 98 uint4 (pad col = 0)
    int acc = 0;
#pragma unroll 7
    for (int i = 0; i < NCHP / 4; ++i) {
      uint4 v = row[i];
      acc += (int)(v.x + v.y + v.z + v.w);
    }
    c = acc;
  }
  s[t] = c;
  __syncthreads();
  for (int off = 1; off < 512; off <<= 1) {
    int v = (t >= off) ? s[t - off] : 0;
    __syncthreads();
    s[t] += v;
    __syncthreads();
  }
  if (t < NBUCK) {
    int b = s[t] - c;
    bucket_base[t] = b;
    bucket_cursor[t] = b;
  }
  if (t == NBUCK) bucket_base[NBUCK] = s[NBUCK - 1];
}

// chunk-local LDS reorder, then bucket-contiguous coalesced writes
__global__ __launch_bounds__(256) void binned_scatter_kernel(const int* __restrict__ src,
                                                             const int* __restrict__ dst,
                                                             int* __restrict__ bucket_cursor,
                                                             unsigned* __restrict__ pairs) {
  __shared__ int lcnt[NBUCK];
  __shared__ int lscan[NBUCK];
  __shared__ int gb[NBUCK];
  __shared__ unsigned ebuf[CHUNK];
  __shared__ unsigned short bbuf[CHUNK];
  int t = threadIdx.x;
  int e_base = blockIdx.x * CHUNK;
  for (int i = t; i < NBUCK; i += 256) lcnt[i] = 0;
  __syncthreads();

  int myb[EPT], myrank[EPT];
  unsigned mye[EPT];
#pragma unroll
  for (int j = 0; j < EPT; ++j) {
    int e = e_base + j * 256 + t;
    if (e < NE) {
      int d = dst[e];
      mye[j] = (unsigned)src[e] | ((unsigned)(d & 255) << 24);
      myb[j] = d >> 8;
      myrank[j] = atomicAdd(&lcnt[d >> 8], 1);
    } else {
      myb[j] = -1;
    }
  }
  __syncthreads();

  lscan[t] = lcnt[t];
  if (256 + t < NBUCK) lscan[256 + t] = lcnt[256 + t];
  __syncthreads();
  for (int off = 1; off < 512; off <<= 1) {
    int v0 = (t >= off) ? lscan[t - off] : 0;
    int v1 = 0;
    int i1 = 256 + t;
    if (i1 < NBUCK) v1 = lscan[i1 - off];
    __syncthreads();
    if (t >= off) lscan[t] += v0;
    if (i1 < NBUCK) lscan[i1] += v1;
    __syncthreads();
  }

#pragma unroll
  for (int j = 0; j < EPT; ++j)
    if (myb[j] >= 0) {
      int b = myb[j];
      int lpos = lscan[b] - lcnt[b] + myrank[j];
      ebuf[lpos] = mye[j];
      bbuf[lpos] = (unsigned short)b;
    }
  for (int i = t; i < NBUCK; i += 256)
    if (lcnt[i] > 0) gb[i] = atomicAdd(&bucket_cursor[i], lcnt[i]);
  __syncthreads();

  int chunk_n = min(CHUNK, NE - e_base);
  for (int s2 = t; s2 < chunk_n; s2 += 256) {
    int b = bbuf[s2];
    int g = gb[b] + (s2 - (lscan[b] - lcnt[b]));
    pairs[g] = ebuf[s2];
  }
}

// one workgroup per bucket: per-node count, local scan -> row_start, fine scatter.
__global__ __launch_bounds__(256) void bucket_build_kernel(const unsigned* __restrict__ pairs,
                                                           const int* __restrict__ bucket_base,
                                                           int* __restrict__ row_start,
                                                           int* __restrict__ nbr,
                                                           float* __restrict__ inv_deg) {
  __shared__ int cnt[256], loc[256], cur[256];
  __shared__ unsigned ec[BCAP];
  int b = blockIdx.x;
  int t = threadIdx.x;
  int nbase = b << 8;
  int e0 = bucket_base[b], e1 = bucket_base[b + 1];
  int n = e1 - e0;
  bool fits = (n <= BCAP);
  cnt[t] = 0;
  __syncthreads();
  if (fits) {
    for (int e = t; e < n; e += 256) {
      unsigned pr = pairs[e0 + e];
      ec[e] = pr;
      atomicAdd(&cnt[pr >> 24], 1);
    }
  } else {
    for (int e = e0 + t; e < e1; e += 256) atomicAdd(&cnt[(int)(pairs[e] >> 24)], 1);
  }
  __syncthreads();
  loc[t] = cnt[t];
  __syncthreads();
  for (int off = 1; off < 256; off <<= 1) {
    int v = (t >= off) ? loc[t - off] : 0;
    __syncthreads();
    loc[t] += v;
    __syncthreads();
  }
  int excl = loc[t] - cnt[t];
  int node = nbase + t;
  if (node < NN) {
    row_start[node] = e0 + excl;
    inv_deg[node] = 1.0f / (float)(cnt[t] > 1 ? cnt[t] : 1);
  }
  cur[t] = excl;
  if (b == NBUCK - 1 && t == 0) row_start[NN] = NE;
  __syncthreads();
  if (fits) {
    for (int e = t; e < n; e += 256) {
      unsigned pr = ec[e];
      int d = (int)(pr >> 24);
      int p = atomicAdd(&cur[d], 1);
      nbr[e0 + p] = (int)(pr & 0xFFFFFFu);
    }
  } else {
    for (int e = e0 + t; e < e1; e += 256) {
      unsigned pr = pairs[e];
      int d = (int)(pr >> 24);
      int p = atomicAdd(&cur[d], 1);
      nbr[e0 + p] = (int)(pr & 0xFFFFFFu);
    }
  }
}

// ---------------- mean aggregation: fp8 in (128B rows), f16 out; 8 lanes/node ----------------
__global__ __launch_bounds__(256) void agg_kernel(const unsigned char* __restrict__ X8,
                                                  _Float16* __restrict__ out,
                                                  const int* __restrict__ row_start,
                                                  const int* __restrict__ nbr,
                                                  const float* __restrict__ inv_deg) {
  int g = blockIdx.x * 32 + (threadIdx.x >> 3);
  int ln = threadIdx.x & 7;
  if (g >= NN) return;
  int p0 = row_start[g];
  int p1 = row_start[g + 1];
  const uint4* base = (const uint4*)X8;  // row = 8 uint4 (128 B)
  float a[16];
#pragma unroll
  for (int i = 0; i < 16; ++i) a[i] = 0.f;
  int p = p0;
  for (; p + 3 < p1; p += 4) {
    int s0 = nbr[p], s1 = nbr[p + 1], s2 = nbr[p + 2], s3 = nbr[p + 3];
    uint4 v0 = base[(size_t)s0 * 8 + ln];
    uint4 v1 = base[(size_t)s1 * 8 + ln];
    uint4 v2 = base[(size_t)s2 * 8 + ln];
    uint4 v3 = base[(size_t)s3 * 8 + ln];
    ACCR(v0) ACCR(v1) ACCR(v2) ACCR(v3)
  }
  for (; p < p1; ++p) {
    uint4 v = base[(size_t)nbr[p] * 8 + ln];
    ACCR(v)
  }
  float id = inv_deg[g];
  uint4 o0, o1;
  o0.x = packh(a[0] * id, a[1] * id);
  o0.y = packh(a[2] * id, a[3] * id);
  o0.z = packh(a[4] * id, a[5] * id);
  o0.w = packh(a[6] * id, a[7] * id);
  o1.x = packh(a[8] * id, a[9] * id);
  o1.y = packh(a[10] * id, a[11] * id);
  o1.z = packh(a[12] * id, a[13] * id);
  o1.w = packh(a[14] * id, a[15] * id);
  uint4* ob = (uint4*)out;
  ob[(size_t)g * 16 + ln * 2] = o0;
  ob[(size_t)g * 16 + ln * 2 + 1] = o1;
}

// ---------------- layer 0: h1 = relu([A|x]@Bcat0 + b0); fp8 output only ----------------
__global__ __launch_bounds__(256) void mfma_gemm_kernel(
    const _Float16* __restrict__ A, const _Float16* __restrict__ H,
    const half8v* __restrict__ B, const float* __restrict__ bias,
    unsigned char* __restrict__ out8) {
  __shared__ _Float16 Os[128][LSTR];  // 34.8KB output transpose buffer

  int t = threadIdx.x;
  int w = t >> 6, l = t & 63;
  int R0 = blockIdx.x * 128;
  int lc = l & 15;
  int lg = l >> 4;

  int frow = R0 + w * 32 + lc;
  int fr0 = min(frow, NN - 1);
  int fr1 = min(frow + 16, NN - 1);

  f32x4 acc[2][8];
#pragma unroll
  for (int m = 0; m < 2; ++m)
#pragma unroll
    for (int n = 0; n < 8; ++n) acc[m][n] = (f32x4){0.f, 0.f, 0.f, 0.f};

#pragma unroll
  for (int s = 0; s < 8; ++s) {
    const _Float16* src = (s < 4) ? A : H;
    int koff = (s & 3) * 32 + lg * 8;
    half8v ah0 = *(const half8v*)(src + (size_t)fr0 * D + koff);
    half8v ah1 = *(const half8v*)(src + (size_t)fr1 * D + koff);
    half8v bh[8];
#pragma unroll
    for (int n = 0; n < 8; ++n) bh[n] = B[(s * 8 + n) * 64 + l];
#pragma unroll
    for (int n = 0; n < 8; ++n) {
      acc[0][n] = __builtin_amdgcn_mfma_f32_16x16x32_f16(ah0, bh[n], acc[0][n], 0, 0, 0);
      acc[1][n] = __builtin_amdgcn_mfma_f32_16x16x32_f16(ah1, bh[n], acc[1][n], 0, 0, 0);
    }
  }

  float bcol[8];
#pragma unroll
  for (int n = 0; n < 8; ++n) bcol[n] = bias[n * 16 + lc];
#pragma unroll
  for (int m = 0; m < 2; ++m)
#pragma unroll
    for (int n = 0; n < 8; ++n) {
      int col = n * 16 + lc;
#pragma unroll
      for (int j = 0; j < 4; ++j) {
        int row = w * 32 + m * 16 + lg * 4 + j;
        Os[row][col] = (_Float16)fmaxf(acc[m][n][j] + bcol[n], 0.f);
      }
    }
  __syncthreads();

#pragma unroll
  for (int i = 0; i < 8; ++i) {
    int u = t + 256 * i;          // uint4 index in [0,2048)
    int row = u >> 4, seg = u & 15;
    int gr = R0 + row;
    if (gr < NN) {
      uint4 v = *(const uint4*)&Os[row][seg * 8];
      unsigned w0 = __builtin_amdgcn_cvt_pk_fp8_f32(
          __half2float(__ushort_as_half((unsigned short)(v.x & 0xffff))),
          __half2float(__ushort_as_half((unsigned short)(v.x >> 16))), 0, 0);
      w0 = __builtin_amdgcn_cvt_pk_fp8_f32(
          __half2float(__ushort_as_half((unsigned short)(v.y & 0xffff))),
          __half2float(__ushort_as_half((unsigned short)(v.y >> 16))), w0, 1);
      unsigned w1 = __builtin_amdgcn_cvt_pk_fp8_f32(
          __half2float(__ushort_as_half((unsigned short)(v.z & 0xffff))),
          __half2float(__ushort_as_half((unsigned short)(v.z >> 16))), 0, 0);
      w1 = __builtin_amdgcn_cvt_pk_fp8_f32(
          __half2float(__ushort_as_half((unsigned short)(v.w & 0xffff))),
          __half2float(__ushort_as_half((unsigned short)(v.w >> 16))), w1, 1);
      *(uint2*)(out8 + (size_t)gr * D + seg * 8) = make_uint2(w0, w1);
    }
  }
}

// ---------------- fused layer 1 + layer-2 transform; root h1 read as fp8 ----------------
__global__ __launch_bounds__(256) void mfma_gemm_out_kernel(
    const _Float16* __restrict__ A, const unsigned char* __restrict__ H8,
    const half8v* __restrict__ B, const float* __restrict__ bias,
    const half8v* __restrict__ By2, const float* __restrict__ b2,
    unsigned char* __restrict__ yl8, float* __restrict__ yr) {
  __shared__ union SM {
    _Float16 Os[128][LSTR];                           // 34.8KB h2 tile
    struct { unsigned char Y8[128][64]; float Yr[128][40]; } y;  // 28KB (reuses Os)
  } sm;

  int t = threadIdx.x;
  int w = t >> 6, l = t & 63;
  int R0 = blockIdx.x * 128;
  int lc = l & 15;
  int lg = l >> 4;

  int frow = R0 + w * 32 + lc;
  int fr0 = min(frow, NN - 1);
  int fr1 = min(frow + 16, NN - 1);

  // ---- layer-1 GEMM ----
  f32x4 acc[2][8];
#pragma unroll
  for (int m = 0; m < 2; ++m)
#pragma unroll
    for (int n = 0; n < 8; ++n) acc[m][n] = (f32x4){0.f, 0.f, 0.f, 0.f};

#pragma unroll
  for (int s = 0; s < 8; ++s) {
    int koff = (s & 3) * 32 + lg * 8;
    half8v ah0, ah1;
    if (s < 4) {
      ah0 = *(const half8v*)(A + (size_t)fr0 * D + koff);
      ah1 = *(const half8v*)(A + (size_t)fr1 * D + koff);
    } else {
      ah0 = fp8_to_h8(*(const uint2*)(H8 + (size_t)fr0 * D + koff));
      ah1 = fp8_to_h8(*(const uint2*)(H8 + (size_t)fr1 * D + koff));
    }
    half8v bh[8];
#pragma unroll
    for (int n = 0; n < 8; ++n) bh[n] = B[(s * 8 + n) * 64 + l];
#pragma unroll
    for (int n = 0; n < 8; ++n) {
      acc[0][n] = __builtin_amdgcn_mfma_f32_16x16x32_f16(ah0, bh[n], acc[0][n], 0, 0, 0);
      acc[1][n] = __builtin_amdgcn_mfma_f32_16x16x32_f16(ah1, bh[n], acc[1][n], 0, 0, 0);
    }
  }

  // h2 tile into LDS. Writes land in rows w*32..w*32+31 (this wave's own rows).
  float bcol[8];
#pragma unroll
  for (int n = 0; n < 8; ++n) bcol[n] = bias[n * 16 + lc];
#pragma unroll
  for (int m = 0; m < 2; ++m)
#pragma unroll
    for (int n = 0; n < 8; ++n) {
      int col = n * 16 + lc;
#pragma unroll
      for (int j = 0; j < 4; ++j) {
        int row = w * 32 + m * 16 + lg * 4 + j;
        sm.Os[row][col] = (_Float16)fmaxf(acc[m][n][j] + bcol[n], 0.f);
      }
    }
  // no barrier needed: y-stage A-frags read rows w*32..w*32+31 — same wave's writes.

  // ---- layer-2 transform: y = h2 @ [Wl2|Wr2]^T ----
  f32x4 acc2[2][5];
#pragma unroll
  for (int m = 0; m < 2; ++m)
#pragma unroll
    for (int n = 0; n < 5; ++n) acc2[m][n] = (f32x4){0.f, 0.f, 0.f, 0.f};

#pragma unroll
  for (int s = 0; s < 4; ++s) {
    int koff = s * 32 + lg * 8;
    half8v ah0 = *(const half8v*)&sm.Os[w * 32 + lc][koff];
    half8v ah1 = *(const half8v*)&sm.Os[w * 32 + 16 + lc][koff];
    half8v bh[5];
#pragma unroll
    for (int n = 0; n < 5; ++n) bh[n] = By2[(s * 5 + n) * 64 + l];
#pragma unroll
    for (int n = 0; n < 5; ++n) {
      acc2[0][n] = __builtin_amdgcn_mfma_f32_16x16x32_f16(ah0, bh[n], acc2[0][n], 0, 0, 0);
      acc2[1][n] = __builtin_amdgcn_mfma_f32_16x16x32_f16(ah1, bh[n], acc2[1][n], 0, 0, 0);
    }
  }
  __syncthreads();  // all waves done reading Os; safe to overlay sm.y

  // scatter y: cols 0..39 (Wl half) -> Y8 fp8; cols 40..79 (Wr half) -> Yr (+b2)
#pragma unroll
  for (int m = 0; m < 2; ++m)
#pragma unroll
    for (int n = 0; n < 5; ++n) {
      int col = n * 16 + lc;
#pragma unroll
      for (int j = 0; j < 4; ++j) {
        int row = w * 32 + m * 16 + lg * 4 + j;
        float v = acc2[m][n][j];
        if (col < DOUT) {
          sm.y.Y8[row][col] = f2fp8(v);
        } else {
          sm.y.Yr[row][col - DOUT] = v + b2[col - DOUT];
        }
      }
    }
  if (t < 128) {
    *(uint2*)&sm.y.Y8[t][40] = make_uint2(0, 0);
    *(uint2*)&sm.y.Y8[t][48] = make_uint2(0, 0);
    *(uint2*)&sm.y.Y8[t][56] = make_uint2(0, 0);
  }
  __syncthreads();

  // coalesced stores: yl8 = 1024 uint2 (8 per row), yr = 1280 float4 (10 per row)
#pragma unroll
  for (int i = 0; i < 4; ++i) {
    int u = t + 256 * i;
    int row = u >> 3, seg = u & 7;
    int gr = R0 + row;
    if (gr < NN)
      *(uint2*)(yl8 + (size_t)gr * 64 + seg * 8) = *(const uint2*)&sm.y.Y8[row][seg * 8];
  }
#pragma unroll
  for (int i = 0; i < 5; ++i) {
    int u = t + 256 * i;
    int row = u / 10, seg = u % 10;
    int gr = R0 + row;
    if (gr < NN)
      *(float4*)(yr + (size_t)gr * DOUT + seg * 4) = *(const float4*)&sm.y.Yr[row][seg * 4];
  }
}

// ---------------- fused layer-2 agg + log_softmax: fp8 64B rows, 8 lanes/node ----------------
__global__ __launch_bounds__(256) void agg_out_kernel(const unsigned char* __restrict__ yl8,
                                                      const float* __restrict__ yr,
                                                      const int* __restrict__ row_start,
                                                      const int* __restrict__ nbr,
                                                      const float* __restrict__ inv_deg,
                                                      float* __restrict__ out) {
  int g = blockIdx.x * 32 + (threadIdx.x >> 3);
  int ln = threadIdx.x & 7;
  if (g >= NN) return;
  int p0 = row_start[g];
  int p1 = row_start[g + 1];
  const uint2* base = (const uint2*)yl8;  // row = 8 uint2 (64 B)
  float a[8];
#pragma unroll
  for (int i = 0; i < 8; ++i) a[i] = 0.f;
  int p = p0;
  for (; p + 3 < p1; p += 4) {
    int s0 = nbr[p], s1 = nbr[p + 1], s2 = nbr[p + 2], s3 = nbr[p + 3];
    uint2 v0 = base[(size_t)s0 * 8 + ln];
    uint2 v1 = base[(size_t)s1 * 8 + ln];
    uint2 v2 = base[(size_t)s2 * 8 + ln];
    uint2 v3 = base[(size_t)s3 * 8 + ln];
    ACCR8(v0) ACCR8(v1) ACCR8(v2) ACCR8(v3)
  }
  for (; p < p1; ++p) {
    uint2 v = base[(size_t)nbr[p] * 8 + ln];
    ACCR8(v)
  }
  float id = inv_deg[g];
  float z[8];
#pragma unroll
  for (int i = 0; i < 8; ++i) z[i] = a[i] * id;
  bool valid = (ln < 5);  // lanes 0..4 own cols ln*8..ln*8+7 (40 total)
  if (valid) {
    float4 r0 = *(const float4*)(yr + (size_t)g * DOUT + ln * 8);
    float4 r1 = *(const float4*)(yr + (size_t)g * DOUT + ln * 8 + 4);
    z[0] += r0.x; z[1] += r0.y; z[2] += r0.z; z[3] += r0.w;
    z[4] += r1.x; z[5] += r1.y; z[6] += r1.z; z[7] += r1.w;
  }
  float zm = -INFINITY;
  if (valid)
#pragma unroll
    for (int i = 0; i < 8; ++i) zm = fmaxf(zm, z[i]);
#pragma unroll
  for (int off = 1; off < 8; off <<= 1) zm = fmaxf(zm, __shfl_xor(zm, off, 8));
  float ssum = 0.f;
  if (valid)
#pragma unroll
    for (int i = 0; i < 8; ++i) ssum += expf(z[i] - zm);
#pragma unroll
  for (int off = 1; off < 8; off <<= 1) ssum += __shfl_xor(ssum, off, 8);
  float lse = zm + logf(ssum);
  if (valid) {
    float4 o0 = make_float4(z[0] - lse, z[1] - lse, z[2] - lse, z[3] - lse);
    float4 o1 = make_float4(z[4] - lse, z[5] - lse, z[6] - lse, z[7] - lse);
    *(float4*)(out + (size_t)g * DOUT + ln * 8) = o0;
    *(float4*)(out + (size_t)g * DOUT + ln * 8 + 4) = o1;
  }
}

// ---------------- launch ----------------
extern "C" void kernel_launch(void* const* d_in, const int* in_sizes, int n_in,
                              void* d_out, int out_size, void* d_ws, size_t ws_size,
                              hipStream_t stream) {
  const float* x   = (const float*)d_in[0];
  const int* esrc  = (const int*)d_in[1];
  const int* edst  = (const int*)d_in[2];
  const float* Wl0 = (const float*)d_in[3];
  const float* Wr0 = (const float*)d_in[4];
  const float* b0  = (const float*)d_in[5];
  const float* Wl1 = (const float*)d_in[6];
  const float* Wr1 = (const float*)d_in[7];
  const float* b1  = (const float*)d_in[8];
  const float* Wl2 = (const float*)d_in[9];
  const float* Wr2 = (const float*)d_in[10];
  const float* b2  = (const float*)d_in[11];
  float* out = (float*)d_out;

  char* ws = (char*)d_ws;
  size_t off = 0;
  auto carve = [&](size_t bytes) -> char* {
    char* p = ws + off;
    off = (off + bytes + 255) & ~(size_t)255;
    return p;
  };
  int* partial       = (int*)carve((size_t)NBUCK * NCHP * 4);   // per-chunk histograms
  int* bucket_base   = (int*)carve((size_t)(NBUCK + 1) * 4);
  int* bucket_cursor = (int*)carve((size_t)NBUCK * 4);
  int* row_start     = (int*)carve((size_t)(NN + 1) * 4);
  int* nbr           = (int*)carve((size_t)NE * 4);
  float* inv_deg     = (float*)carve((size_t)NN * 4);
  unsigned* pairs    = (unsigned*)carve((size_t)NE * 4);
  half8v* B0         = (half8v*)carve((size_t)64 * 64 * 16);
  half8v* B1         = (half8v*)carve((size_t)64 * 64 * 16);
  half8v* By2        = (half8v*)carve((size_t)20 * 64 * 16);
  _Float16* xb   = (_Float16*)carve((size_t)NN * D * 2);
  unsigned char* x8    = (unsigned char*)carve((size_t)NN * D);
  _Float16* bufA = (_Float16*)carve((size_t)NN * D * 2);
  unsigned char* bufB8 = (unsigned char*)carve((size_t)NN * D);
  unsigned char* yl8   = (unsigned char*)carve((size_t)NN * 64);
  float* yr      = (float*)carve((size_t)NN * DOUT * 4);
  if (off > ws_size) return;

  const int GRID_AGG = (NN + 31) / 32;       // 3125
  const int GRID_GEMM = (NN + 127) / 128;    // 782
  const int GRID_AO = (NN + 31) / 32;        // 3125
  const int GRID_PREP = 6287 + NCHUNK;       // cvt + planes + hist chunks

  // fused prep (cvt + weight planes + per-chunk histograms)
  prep_all_kernel<<<GRID_PREP, 256, 0, stream>>>(x, xb, x8, Wl0, Wr0, B0,
                                                 Wl1, Wr1, B1, Wl2, Wr2, By2,
                                                 edst, partial);
  // CSR build
  bucket_scan_kernel<<<1, 512, 0, stream>>>(partial, bucket_base, bucket_cursor);
  binned_scatter_kernel<<<NCHUNK, 256, 0, stream>>>(esrc, edst, bucket_cursor, pairs);
  bucket_build_kernel<<<NBUCK, 256, 0, stream>>>(pairs, bucket_base, row_start, nbr, inv_deg);

  // layer 0: agg(x8) -> bufA; h1 = relu([bufA|x]@B0 + b0) -> fp8 only
  agg_kernel<<<GRID_AGG, 256, 0, stream>>>(x8, bufA, row_start, nbr, inv_deg);
  mfma_gemm_kernel<<<GRID_GEMM, 256, 0, stream>>>(bufA, xb, B0, b0, bufB8);
  // layer 1: agg(h1 fp8) -> bufA; fused GEMM (root h1 fp8) + y2 transform
  agg_kernel<<<GRID_AGG, 256, 0, stream>>>(bufB8, bufA, row_start, nbr, inv_deg);
  mfma_gemm_out_kernel<<<GRID_GEMM, 256, 0, stream>>>(bufA, bufB8, B1, b1, By2, b2, yl8, yr);
  // layer 2 aggregation + log_softmax
  agg_out_kernel<<<GRID_AO, 256, 0, stream>>>(yl8, yr, row_start, nbr, inv_deg, out);
}

// Round 20
// 215.460 us; speedup vs baseline: 1.0611x; 1.0611x over previous
//
#include <hip/hip_runtime.h>
#include <hip/hip_fp16.h>
#include <math.h>

#define NN 100000
#define NE 1600000
#define D 128
#define DOUT 40
#define NBUCK 391          // ceil(NN/256): bucket = 256 consecutive nodes
#define CHUNK 4096         // edges per binning workgroup (fat chunks amortize per-block NBUCK scan)
#define NCHUNK 391         // ceil(NE/CHUNK)
#define EPT 16             // CHUNK/256 edges per thread
#define LSTR 136           // LDS row stride in f16: 272B = 17*16B (aligned)
#define BCAP 5120          // bucket_build LDS edge cache capacity

typedef _Float16 half8v __attribute__((ext_vector_type(8)));   // 8 f16 (4 VGPR)
typedef __attribute__((ext_vector_type(4))) float f32x4;

__device__ __forceinline__ unsigned packh(float a, float b) {
  return (unsigned)__half_as_ushort(__float2half_rn(a)) |
         ((unsigned)__half_as_ushort(__float2half_rn(b)) << 16);
}
// fp8 e4m3 (OCP) helpers — HW converts on gfx950
__device__ __forceinline__ unsigned char f2fp8(float v) {
  return (unsigned char)(__builtin_amdgcn_cvt_pk_fp8_f32(v, v, 0, 0) & 0xff);
}
#define CVT2(u, s) __builtin_amdgcn_cvt_pk_f32_fp8((int)(u), s)
// accumulate 16 fp8 (one uint4) into a[0..15]
#define ACCR(v) { auto q = CVT2((v).x, 0); a[0] += q[0]; a[1] += q[1];   \
  q = CVT2((v).x, 1); a[2] += q[0];  a[3] += q[1];                        \
  q = CVT2((v).y, 0); a[4] += q[0];  a[5] += q[1];                        \
  q = CVT2((v).y, 1); a[6] += q[0];  a[7] += q[1];                        \
  q = CVT2((v).z, 0); a[8] += q[0];  a[9] += q[1];                        \
  q = CVT2((v).z, 1); a[10] += q[0]; a[11] += q[1];                       \
  q = CVT2((v).w, 0); a[12] += q[0]; a[13] += q[1];                       \
  q = CVT2((v).w, 1); a[14] += q[0]; a[15] += q[1]; }
// accumulate 8 fp8 (one uint2) into a[0..7]
#define ACCR8(v) { auto q = CVT2((v).x, 0); a[0] += q[0]; a[1] += q[1];  \
  q = CVT2((v).x, 1); a[2] += q[0]; a[3] += q[1];                         \
  q = CVT2((v).y, 0); a[4] += q[0]; a[5] += q[1];                         \
  q = CVT2((v).y, 1); a[6] += q[0]; a[7] += q[1]; }

// 8 fp8 (uint2) -> half8v via HW fp8->f32
__device__ __forceinline__ half8v fp8_to_h8(uint2 u) {
  auto q0 = CVT2(u.x, 0);
  auto q1 = CVT2(u.x, 1);
  auto q2 = CVT2(u.y, 0);
  auto q3 = CVT2(u.y, 1);
  half8v h;
  h[0] = (_Float16)q0[0]; h[1] = (_Float16)q0[1];
  h[2] = (_Float16)q1[0]; h[3] = (_Float16)q1[1];
  h[4] = (_Float16)q2[0]; h[5] = (_Float16)q2[1];
  h[6] = (_Float16)q3[0]; h[7] = (_Float16)q3[1];
  return h;
}

// ---------------- fused prep: x->f16+fp8, weight planes, bucket_cnt zero ----------------
__global__ __launch_bounds__(256) void prep_all_kernel(
    const float* __restrict__ x, _Float16* __restrict__ xb, unsigned char* __restrict__ x8,
    const float* __restrict__ Wl0, const float* __restrict__ Wr0, half8v* __restrict__ B0,
    const float* __restrict__ Wl1, const float* __restrict__ Wr1, half8v* __restrict__ B1,
    const float* __restrict__ Wl2, const float* __restrict__ Wr2, half8v* __restrict__ By2,
    int* __restrict__ bucket_cnt) {
  int bid = blockIdx.x;
  int t = threadIdx.x;
  if (bid < 6250) {  // cvt
    int i = (bid * 256 + t) * 8;
    float4 v0 = *(const float4*)(x + i);
    float4 v1 = *(const float4*)(x + i + 4);
    uint4 oh;
    oh.x = packh(v0.x, v0.y);
    oh.y = packh(v0.z, v0.w);
    oh.z = packh(v1.x, v1.y);
    oh.w = packh(v1.z, v1.w);
    *(uint4*)(xb + i) = oh;
    unsigned w0 = __builtin_amdgcn_cvt_pk_fp8_f32(v0.x, v0.y, 0, 0);
    w0 = __builtin_amdgcn_cvt_pk_fp8_f32(v0.z, v0.w, w0, 1);
    unsigned w1 = __builtin_amdgcn_cvt_pk_fp8_f32(v1.x, v1.y, 0, 0);
    w1 = __builtin_amdgcn_cvt_pk_fp8_f32(v1.z, v1.w, w1, 1);
    *(uint2*)(x8 + i) = make_uint2(w0, w1);
  } else if (bid < 6282) {  // B0 / B1 planes
    const float* Wl = (bid < 6266) ? Wl0 : Wl1;
    const float* Wr = (bid < 6266) ? Wr0 : Wr1;
    half8v* P = (bid < 6266) ? B0 : B1;
    int rel = (bid < 6266) ? bid - 6250 : bid - 6266;
    int ob = rel * 4 + (t >> 6);  // 0..63
    int l = t & 63;
    int s = ob >> 3, n = ob & 7;
    int k0 = s * 32 + (l >> 4) * 8;
    int c = n * 16 + (l & 15);
    const float* W = (k0 < 128) ? Wl : Wr;
    int kb = (k0 < 128) ? k0 : k0 - 128;
    half8v h;
#pragma unroll
    for (int i = 0; i < 8; ++i) h[i] = (_Float16)W[c * 128 + kb + i];
    P[ob * 64 + l] = h;
  } else if (bid < 6287) {  // By2 plane: cols 0..39 = Wl2 rows, 40..79 = Wr2 rows
    int rel = bid - 6282;
    int ob = rel * 4 + (t >> 6);  // 0..19
    int l = t & 63;
    int s = ob / 5, n = ob % 5;
    int k0 = s * 32 + (l >> 4) * 8;
    int c = n * 16 + (l & 15);
    const float* W = (c < DOUT) ? Wl2 : Wr2;
    int row = (c < DOUT) ? c : c - DOUT;
    half8v h;
#pragma unroll
    for (int i = 0; i < 8; ++i) h[i] = (_Float16)W[row * 128 + k0 + i];
    By2[ob * 64 + l] = h;
  } else {  // zero bucket_cnt
    for (int i = t; i < NBUCK; i += 256) bucket_cnt[i] = 0;
  }
}

// ---------------- CSR build: bucketed ----------------
__global__ __launch_bounds__(256) void bucket_hist_kernel(const int* __restrict__ dst,
                                                          int* __restrict__ bucket_cnt) {
  __shared__ int bc[NBUCK];
  int t = threadIdx.x;
  for (int i = t; i < NBUCK; i += 256) bc[i] = 0;
  __syncthreads();
  int e_base = blockIdx.x * CHUNK;
#pragma unroll
  for (int j = 0; j < EPT; ++j) {
    int e = e_base + j * 256 + t;
    if (e < NE) atomicAdd(&bc[dst[e] >> 8], 1);
  }
  __syncthreads();
  for (int i = t; i < NBUCK; i += 256)
    if (bc[i]) atomicAdd(&bucket_cnt[i], bc[i]);
}

__global__ __launch_bounds__(512) void bucket_scan_kernel(const int* __restrict__ bucket_cnt,
                                                          int* __restrict__ bucket_base,
                                                          int* __restrict__ bucket_cursor) {
  __shared__ int s[512];
  int t = threadIdx.x;
  int c = (t < NBUCK) ? bucket_cnt[t] : 0;
  s[t] = c;
  __syncthreads();
  for (int off = 1; off < 512; off <<= 1) {
    int v = (t >= off) ? s[t - off] : 0;
    __syncthreads();
    s[t] += v;
    __syncthreads();
  }
  if (t < NBUCK) {
    int b = s[t] - c;
    bucket_base[t] = b;
    bucket_cursor[t] = b;
  }
  if (t == NBUCK) bucket_base[NBUCK] = s[NBUCK - 1];
}

// chunk-local LDS reorder, then bucket-contiguous coalesced writes
__global__ __launch_bounds__(256) void binned_scatter_kernel(const int* __restrict__ src,
                                                             const int* __restrict__ dst,
                                                             int* __restrict__ bucket_cursor,
                                                             unsigned* __restrict__ pairs) {
  __shared__ int lcnt[NBUCK];
  __shared__ int lscan[NBUCK];
  __shared__ int gb[NBUCK];
  __shared__ unsigned ebuf[CHUNK];
  __shared__ unsigned short bbuf[CHUNK];
  int t = threadIdx.x;
  int e_base = blockIdx.x * CHUNK;
  for (int i = t; i < NBUCK; i += 256) lcnt[i] = 0;
  __syncthreads();

  int myb[EPT], myrank[EPT];
  unsigned mye[EPT];
#pragma unroll
  for (int j = 0; j < EPT; ++j) {
    int e = e_base + j * 256 + t;
    if (e < NE) {
      int d = dst[e];
      mye[j] = (unsigned)src[e] | ((unsigned)(d & 255) << 24);
      myb[j] = d >> 8;
      myrank[j] = atomicAdd(&lcnt[d >> 8], 1);
    } else {
      myb[j] = -1;
    }
  }
  __syncthreads();

  lscan[t] = lcnt[t];
  if (256 + t < NBUCK) lscan[256 + t] = lcnt[256 + t];
  __syncthreads();
  for (int off = 1; off < 512; off <<= 1) {
    int v0 = (t >= off) ? lscan[t - off] : 0;
    int v1 = 0;
    int i1 = 256 + t;
    if (i1 < NBUCK) v1 = lscan[i1 - off];
    __syncthreads();
    if (t >= off) lscan[t] += v0;
    if (i1 < NBUCK) lscan[i1] += v1;
    __syncthreads();
  }

#pragma unroll
  for (int j = 0; j < EPT; ++j)
    if (myb[j] >= 0) {
      int b = myb[j];
      int lpos = lscan[b] - lcnt[b] + myrank[j];
      ebuf[lpos] = mye[j];
      bbuf[lpos] = (unsigned short)b;
    }
  for (int i = t; i < NBUCK; i += 256)
    if (lcnt[i] > 0) gb[i] = atomicAdd(&bucket_cursor[i], lcnt[i]);
  __syncthreads();

  int chunk_n = min(CHUNK, NE - e_base);
  for (int s2 = t; s2 < chunk_n; s2 += 256) {
    int b = bbuf[s2];
    int g = gb[b] + (s2 - (lscan[b] - lcnt[b]));
    pairs[g] = ebuf[s2];
  }
}

// one workgroup per bucket: per-node count, local scan -> row_start, fine scatter.
__global__ __launch_bounds__(256) void bucket_build_kernel(const unsigned* __restrict__ pairs,
                                                           const int* __restrict__ bucket_base,
                                                           int* __restrict__ row_start,
                                                           int* __restrict__ nbr,
                                                           float* __restrict__ inv_deg) {
  __shared__ int cnt[256], loc[256], cur[256];
  __shared__ unsigned ec[BCAP];
  int b = blockIdx.x;
  int t = threadIdx.x;
  int nbase = b << 8;
  int e0 = bucket_base[b], e1 = bucket_base[b + 1];
  int n = e1 - e0;
  bool fits = (n <= BCAP);
  cnt[t] = 0;
  __syncthreads();
  if (fits) {
    for (int e = t; e < n; e += 256) {
      unsigned pr = pairs[e0 + e];
      ec[e] = pr;
      atomicAdd(&cnt[pr >> 24], 1);
    }
  } else {
    for (int e = e0 + t; e < e1; e += 256) atomicAdd(&cnt[(int)(pairs[e] >> 24)], 1);
  }
  __syncthreads();
  loc[t] = cnt[t];
  __syncthreads();
  for (int off = 1; off < 256; off <<= 1) {
    int v = (t >= off) ? loc[t - off] : 0;
    __syncthreads();
    loc[t] += v;
    __syncthreads();
  }
  int excl = loc[t] - cnt[t];
  int node = nbase + t;
  if (node < NN) {
    row_start[node] = e0 + excl;
    inv_deg[node] = 1.0f / (float)(cnt[t] > 1 ? cnt[t] : 1);
  }
  cur[t] = excl;
  if (b == NBUCK - 1 && t == 0) row_start[NN] = NE;
  __syncthreads();
  if (fits) {
    for (int e = t; e < n; e += 256) {
      unsigned pr = ec[e];
      int d = (int)(pr >> 24);
      int p = atomicAdd(&cur[d], 1);
      nbr[e0 + p] = (int)(pr & 0xFFFFFFu);
    }
  } else {
    for (int e = e0 + t; e < e1; e += 256) {
      unsigned pr = pairs[e];
      int d = (int)(pr >> 24);
      int p = atomicAdd(&cur[d], 1);
      nbr[e0 + p] = (int)(pr & 0xFFFFFFu);
    }
  }
}

// ---------------- mean aggregation: fp8 in (128B rows), f16 out; 8 lanes/node ----------------
__global__ __launch_bounds__(256) void agg_kernel(const unsigned char* __restrict__ X8,
                                                  _Float16* __restrict__ out,
                                                  const int* __restrict__ row_start,
                                                  const int* __restrict__ nbr,
                                                  const float* __restrict__ inv_deg) {
  int g = blockIdx.x * 32 + (threadIdx.x >> 3);
  int ln = threadIdx.x & 7;
  if (g >= NN) return;
  int p0 = row_start[g];
  int p1 = row_start[g + 1];
  const uint4* base = (const uint4*)X8;  // row = 8 uint4 (128 B)
  float a[16];
#pragma unroll
  for (int i = 0; i < 16; ++i) a[i] = 0.f;
  int p = p0;
  for (; p + 3 < p1; p += 4) {
    int s0 = nbr[p], s1 = nbr[p + 1], s2 = nbr[p + 2], s3 = nbr[p + 3];
    uint4 v0 = base[(size_t)s0 * 8 + ln];
    uint4 v1 = base[(size_t)s1 * 8 + ln];
    uint4 v2 = base[(size_t)s2 * 8 + ln];
    uint4 v3 = base[(size_t)s3 * 8 + ln];
    ACCR(v0) ACCR(v1) ACCR(v2) ACCR(v3)
  }
  for (; p < p1; ++p) {
    uint4 v = base[(size_t)nbr[p] * 8 + ln];
    ACCR(v)
  }
  float id = inv_deg[g];
  uint4 o0, o1;
  o0.x = packh(a[0] * id, a[1] * id);
  o0.y = packh(a[2] * id, a[3] * id);
  o0.z = packh(a[4] * id, a[5] * id);
  o0.w = packh(a[6] * id, a[7] * id);
  o1.x = packh(a[8] * id, a[9] * id);
  o1.y = packh(a[10] * id, a[11] * id);
  o1.z = packh(a[12] * id, a[13] * id);
  o1.w = packh(a[14] * id, a[15] * id);
  uint4* ob = (uint4*)out;
  ob[(size_t)g * 16 + ln * 2] = o0;
  ob[(size_t)g * 16 + ln * 2 + 1] = o1;
}

// ---------------- layer 0: h1 = relu([A|x]@Bcat0 + b0); fp8 output only ----------------
__global__ __launch_bounds__(256) void mfma_gemm_kernel(
    const _Float16* __restrict__ A, const _Float16* __restrict__ H,
    const half8v* __restrict__ B, const float* __restrict__ bias,
    unsigned char* __restrict__ out8) {
  __shared__ _Float16 Os[128][LSTR];  // 34.8KB output transpose buffer

  int t = threadIdx.x;
  int w = t >> 6, l = t & 63;
  int R0 = blockIdx.x * 128;
  int lc = l & 15;
  int lg = l >> 4;

  int frow = R0 + w * 32 + lc;
  int fr0 = min(frow, NN - 1);
  int fr1 = min(frow + 16, NN - 1);

  f32x4 acc[2][8];
#pragma unroll
  for (int m = 0; m < 2; ++m)
#pragma unroll
    for (int n = 0; n < 8; ++n) acc[m][n] = (f32x4){0.f, 0.f, 0.f, 0.f};

#pragma unroll
  for (int s = 0; s < 8; ++s) {
    const _Float16* src = (s < 4) ? A : H;
    int koff = (s & 3) * 32 + lg * 8;
    half8v ah0 = *(const half8v*)(src + (size_t)fr0 * D + koff);
    half8v ah1 = *(const half8v*)(src + (size_t)fr1 * D + koff);
    half8v bh[8];
#pragma unroll
    for (int n = 0; n < 8; ++n) bh[n] = B[(s * 8 + n) * 64 + l];
#pragma unroll
    for (int n = 0; n < 8; ++n) {
      acc[0][n] = __builtin_amdgcn_mfma_f32_16x16x32_f16(ah0, bh[n], acc[0][n], 0, 0, 0);
      acc[1][n] = __builtin_amdgcn_mfma_f32_16x16x32_f16(ah1, bh[n], acc[1][n], 0, 0, 0);
    }
  }

  float bcol[8];
#pragma unroll
  for (int n = 0; n < 8; ++n) bcol[n] = bias[n * 16 + lc];
#pragma unroll
  for (int m = 0; m < 2; ++m)
#pragma unroll
    for (int n = 0; n < 8; ++n) {
      int col = n * 16 + lc;
#pragma unroll
      for (int j = 0; j < 4; ++j) {
        int row = w * 32 + m * 16 + lg * 4 + j;
        Os[row][col] = (_Float16)fmaxf(acc[m][n][j] + bcol[n], 0.f);
      }
    }
  __syncthreads();

#pragma unroll
  for (int i = 0; i < 8; ++i) {
    int u = t + 256 * i;          // uint4 index in [0,2048)
    int row = u >> 4, seg = u & 15;
    int gr = R0 + row;
    if (gr < NN) {
      uint4 v = *(const uint4*)&Os[row][seg * 8];
      unsigned w0 = __builtin_amdgcn_cvt_pk_fp8_f32(
          __half2float(__ushort_as_half((unsigned short)(v.x & 0xffff))),
          __half2float(__ushort_as_half((unsigned short)(v.x >> 16))), 0, 0);
      w0 = __builtin_amdgcn_cvt_pk_fp8_f32(
          __half2float(__ushort_as_half((unsigned short)(v.y & 0xffff))),
          __half2float(__ushort_as_half((unsigned short)(v.y >> 16))), w0, 1);
      unsigned w1 = __builtin_amdgcn_cvt_pk_fp8_f32(
          __half2float(__ushort_as_half((unsigned short)(v.z & 0xffff))),
          __half2float(__ushort_as_half((unsigned short)(v.z >> 16))), 0, 0);
      w1 = __builtin_amdgcn_cvt_pk_fp8_f32(
          __half2float(__ushort_as_half((unsigned short)(v.w & 0xffff))),
          __half2float(__ushort_as_half((unsigned short)(v.w >> 16))), w1, 1);
      *(uint2*)(out8 + (size_t)gr * D + seg * 8) = make_uint2(w0, w1);
    }
  }
}

// ---------------- fused layer 1 + layer-2 transform; root h1 read as fp8 ----------------
__global__ __launch_bounds__(256) void mfma_gemm_out_kernel(
    const _Float16* __restrict__ A, const unsigned char* __restrict__ H8,
    const half8v* __restrict__ B, const float* __restrict__ bias,
    const half8v* __restrict__ By2, const float* __restrict__ b2,
    unsigned char* __restrict__ yl8, float* __restrict__ yr) {
  __shared__ union SM {
    _Float16 Os[128][LSTR];                           // 34.8KB h2 tile
    struct { unsigned char Y8[128][64]; float Yr[128][40]; } y;  // 28KB (reuses Os)
  } sm;

  int t = threadIdx.x;
  int w = t >> 6, l = t & 63;
  int R0 = blockIdx.x * 128;
  int lc = l & 15;
  int lg = l >> 4;

  int frow = R0 + w * 32 + lc;
  int fr0 = min(frow, NN - 1);
  int fr1 = min(frow + 16, NN - 1);

  // ---- layer-1 GEMM ----
  f32x4 acc[2][8];
#pragma unroll
  for (int m = 0; m < 2; ++m)
#pragma unroll
    for (int n = 0; n < 8; ++n) acc[m][n] = (f32x4){0.f, 0.f, 0.f, 0.f};

#pragma unroll
  for (int s = 0; s < 8; ++s) {
    int koff = (s & 3) * 32 + lg * 8;
    half8v ah0, ah1;
    if (s < 4) {
      ah0 = *(const half8v*)(A + (size_t)fr0 * D + koff);
      ah1 = *(const half8v*)(A + (size_t)fr1 * D + koff);
    } else {
      ah0 = fp8_to_h8(*(const uint2*)(H8 + (size_t)fr0 * D + koff));
      ah1 = fp8_to_h8(*(const uint2*)(H8 + (size_t)fr1 * D + koff));
    }
    half8v bh[8];
#pragma unroll
    for (int n = 0; n < 8; ++n) bh[n] = B[(s * 8 + n) * 64 + l];
#pragma unroll
    for (int n = 0; n < 8; ++n) {
      acc[0][n] = __builtin_amdgcn_mfma_f32_16x16x32_f16(ah0, bh[n], acc[0][n], 0, 0, 0);
      acc[1][n] = __builtin_amdgcn_mfma_f32_16x16x32_f16(ah1, bh[n], acc[1][n], 0, 0, 0);
    }
  }

  // h2 tile into LDS. Writes land in rows w*32..w*32+31 (this wave's own rows).
  float bcol[8];
#pragma unroll
  for (int n = 0; n < 8; ++n) bcol[n] = bias[n * 16 + lc];
#pragma unroll
  for (int m = 0; m < 2; ++m)
#pragma unroll
    for (int n = 0; n < 8; ++n) {
      int col = n * 16 + lc;
#pragma unroll
      for (int j = 0; j < 4; ++j) {
        int row = w * 32 + m * 16 + lg * 4 + j;
        sm.Os[row][col] = (_Float16)fmaxf(acc[m][n][j] + bcol[n], 0.f);
      }
    }
  // no barrier needed: y-stage A-frags read rows w*32..w*32+31 — same wave's writes.

  // ---- layer-2 transform: y = h2 @ [Wl2|Wr2]^T ----
  f32x4 acc2[2][5];
#pragma unroll
  for (int m = 0; m < 2; ++m)
#pragma unroll
    for (int n = 0; n < 5; ++n) acc2[m][n] = (f32x4){0.f, 0.f, 0.f, 0.f};

#pragma unroll
  for (int s = 0; s < 4; ++s) {
    int koff = s * 32 + lg * 8;
    half8v ah0 = *(const half8v*)&sm.Os[w * 32 + lc][koff];
    half8v ah1 = *(const half8v*)&sm.Os[w * 32 + 16 + lc][koff];
    half8v bh[5];
#pragma unroll
    for (int n = 0; n < 5; ++n) bh[n] = By2[(s * 5 + n) * 64 + l];
#pragma unroll
    for (int n = 0; n < 5; ++n) {
      acc2[0][n] = __builtin_amdgcn_mfma_f32_16x16x32_f16(ah0, bh[n], acc2[0][n], 0, 0, 0);
      acc2[1][n] = __builtin_amdgcn_mfma_f32_16x16x32_f16(ah1, bh[n], acc2[1][n], 0, 0, 0);
    }
  }
  __syncthreads();  // all waves done reading Os; safe to overlay sm.y

  // scatter y: cols 0..39 (Wl half) -> Y8 fp8; cols 40..79 (Wr half) -> Yr (+b2)
#pragma unroll
  for (int m = 0; m < 2; ++m)
#pragma unroll
    for (int n = 0; n < 5; ++n) {
      int col = n * 16 + lc;
#pragma unroll
      for (int j = 0; j < 4; ++j) {
        int row = w * 32 + m * 16 + lg * 4 + j;
        float v = acc2[m][n][j];
        if (col < DOUT) {
          sm.y.Y8[row][col] = f2fp8(v);
        } else {
          sm.y.Yr[row][col - DOUT] = v + b2[col - DOUT];
        }
      }
    }
  if (t < 128) {
    *(uint2*)&sm.y.Y8[t][40] = make_uint2(0, 0);
    *(uint2*)&sm.y.Y8[t][48] = make_uint2(0, 0);
    *(uint2*)&sm.y.Y8[t][56] = make_uint2(0, 0);
  }
  __syncthreads();

  // coalesced stores: yl8 = 1024 uint2 (8 per row), yr = 1280 float4 (10 per row)
#pragma unroll
  for (int i = 0; i < 4; ++i) {
    int u = t + 256 * i;
    int row = u >> 3, seg = u & 7;
    int gr = R0 + row;
    if (gr < NN)
      *(uint2*)(yl8 + (size_t)gr * 64 + seg * 8) = *(const uint2*)&sm.y.Y8[row][seg * 8];
  }
#pragma unroll
  for (int i = 0; i < 5; ++i) {
    int u = t + 256 * i;
    int row = u / 10, seg = u % 10;
    int gr = R0 + row;
    if (gr < NN)
      *(float4*)(yr + (size_t)gr * DOUT + seg * 4) = *(const float4*)&sm.y.Yr[row][seg * 4];
  }
}

// ---------------- fused layer-2 agg + log_softmax: fp8 64B rows, 8 lanes/node ----------------
__global__ __launch_bounds__(256) void agg_out_kernel(const unsigned char* __restrict__ yl8,
                                                      const float* __restrict__ yr,
                                                      const int* __restrict__ row_start,
                                                      const int* __restrict__ nbr,
                                                      const float* __restrict__ inv_deg,
                                                      float* __restrict__ out) {
  int g = blockIdx.x * 32 + (threadIdx.x >> 3);
  int ln = threadIdx.x & 7;
  if (g >= NN) return;
  int p0 = row_start[g];
  int p1 = row_start[g + 1];
  const uint2* base = (const uint2*)yl8;  // row = 8 uint2 (64 B)
  float a[8];
#pragma unroll
  for (int i = 0; i < 8; ++i) a[i] = 0.f;
  int p = p0;
  for (; p + 3 < p1; p += 4) {
    int s0 = nbr[p], s1 = nbr[p + 1], s2 = nbr[p + 2], s3 = nbr[p + 3];
    uint2 v0 = base[(size_t)s0 * 8 + ln];
    uint2 v1 = base[(size_t)s1 * 8 + ln];
    uint2 v2 = base[(size_t)s2 * 8 + ln];
    uint2 v3 = base[(size_t)s3 * 8 + ln];
    ACCR8(v0) ACCR8(v1) ACCR8(v2) ACCR8(v3)
  }
  for (; p < p1; ++p) {
    uint2 v = base[(size_t)nbr[p] * 8 + ln];
    ACCR8(v)
  }
  float id = inv_deg[g];
  float z[8];
#pragma unroll
  for (int i = 0; i < 8; ++i) z[i] = a[i] * id;
  bool valid = (ln < 5);  // lanes 0..4 own cols ln*8..ln*8+7 (40 total)
  if (valid) {
    float4 r0 = *(const float4*)(yr + (size_t)g * DOUT + ln * 8);
    float4 r1 = *(const float4*)(yr + (size_t)g * DOUT + ln * 8 + 4);
    z[0] += r0.x; z[1] += r0.y; z[2] += r0.z; z[3] += r0.w;
    z[4] += r1.x; z[5] += r1.y; z[6] += r1.z; z[7] += r1.w;
  }
  float zm = -INFINITY;
  if (valid)
#pragma unroll
    for (int i = 0; i < 8; ++i) zm = fmaxf(zm, z[i]);
#pragma unroll
  for (int off = 1; off < 8; off <<= 1) zm = fmaxf(zm, __shfl_xor(zm, off, 8));
  float ssum = 0.f;
  if (valid)
#pragma unroll
    for (int i = 0; i < 8; ++i) ssum += expf(z[i] - zm);
#pragma unroll
  for (int off = 1; off < 8; off <<= 1) ssum += __shfl_xor(ssum, off, 8);
  float lse = zm + logf(ssum);
  if (valid) {
    float4 o0 = make_float4(z[0] - lse, z[1] - lse, z[2] - lse, z[3] - lse);
    float4 o1 = make_float4(z[4] - lse, z[5] - lse, z[6] - lse, z[7] - lse);
    *(float4*)(out + (size_t)g * DOUT + ln * 8) = o0;
    *(float4*)(out + (size_t)g * DOUT + ln * 8 + 4) = o1;
  }
}

// ---------------- launch ----------------
extern "C" void kernel_launch(void* const* d_in, const int* in_sizes, int n_in,
                              void* d_out, int out_size, void* d_ws, size_t ws_size,
                              hipStream_t stream) {
  const float* x   = (const float*)d_in[0];
  const int* esrc  = (const int*)d_in[1];
  const int* edst  = (const int*)d_in[2];
  const float* Wl0 = (const float*)d_in[3];
  const float* Wr0 = (const float*)d_in[4];
  const float* b0  = (const float*)d_in[5];
  const float* Wl1 = (const float*)d_in[6];
  const float* Wr1 = (const float*)d_in[7];
  const float* b1  = (const float*)d_in[8];
  const float* Wl2 = (const float*)d_in[9];
  const float* Wr2 = (const float*)d_in[10];
  const float* b2  = (const float*)d_in[11];
  float* out = (float*)d_out;

  char* ws = (char*)d_ws;
  size_t off = 0;
  auto carve = [&](size_t bytes) -> char* {
    char* p = ws + off;
    off = (off + bytes + 255) & ~(size_t)255;
    return p;
  };
  int* bucket_cnt    = (int*)carve((size_t)NBUCK * 4);
  int* bucket_base   = (int*)carve((size_t)(NBUCK + 1) * 4);
  int* bucket_cursor = (int*)carve((size_t)NBUCK * 4);
  int* row_start     = (int*)carve((size_t)(NN + 1) * 4);
  int* nbr           = (int*)carve((size_t)NE * 4);
  float* inv_deg     = (float*)carve((size_t)NN * 4);
  unsigned* pairs    = (unsigned*)carve((size_t)NE * 4);
  half8v* B0         = (half8v*)carve((size_t)64 * 64 * 16);
  half8v* B1         = (half8v*)carve((size_t)64 * 64 * 16);
  half8v* By2        = (half8v*)carve((size_t)20 * 64 * 16);
  _Float16* xb   = (_Float16*)carve((size_t)NN * D * 2);
  unsigned char* x8    = (unsigned char*)carve((size_t)NN * D);
  _Float16* bufA = (_Float16*)carve((size_t)NN * D * 2);
  unsigned char* bufB8 = (unsigned char*)carve((size_t)NN * D);
  unsigned char* yl8   = (unsigned char*)carve((size_t)NN * 64);
  float* yr      = (float*)carve((size_t)NN * DOUT * 4);
  if (off > ws_size) return;

  const int GRID_AGG = (NN + 31) / 32;       // 3125
  const int GRID_GEMM = (NN + 127) / 128;    // 782
  const int GRID_AO = (NN + 31) / 32;        // 3125
  const int GRID_PREP = 6288;                // 6250 cvt + 16 B0 + 16 B1 + 5 By2 + 1 zero

  // fused prep (cvt + weight planes + bucket_cnt zero)
  prep_all_kernel<<<GRID_PREP, 256, 0, stream>>>(x, xb, x8, Wl0, Wr0, B0,
                                                 Wl1, Wr1, B1, Wl2, Wr2, By2, bucket_cnt);
  // CSR build (bucketed)
  bucket_hist_kernel<<<NCHUNK, 256, 0, stream>>>(edst, bucket_cnt);
  bucket_scan_kernel<<<1, 512, 0, stream>>>(bucket_cnt, bucket_base, bucket_cursor);
  binned_scatter_kernel<<<NCHUNK, 256, 0, stream>>>(esrc, edst, bucket_cursor, pairs);
  bucket_build_kernel<<<NBUCK, 256, 0, stream>>>(pairs, bucket_base, row_start, nbr, inv_deg);

  // layer 0: agg(x8) -> bufA; h1 = relu([bufA|x]@B0 + b0) -> fp8 only
  agg_kernel<<<GRID_AGG, 256, 0, stream>>>(x8, bufA, row_start, nbr, inv_deg);
  mfma_gemm_kernel<<<GRID_GEMM, 256, 0, stream>>>(bufA, xb, B0, b0, bufB8);
  // layer 1: agg(h1 fp8) -> bufA; fused GEMM (root h1 fp8) + y2 transform
  agg_kernel<<<GRID_AGG, 256, 0, stream>>>(bufB8, bufA, row_start, nbr, inv_deg);
  mfma_gemm_out_kernel<<<GRID_GEMM, 256, 0, stream>>>(bufA, bufB8, B1, b1, By2, b2, yl8, yr);
  // layer 2 aggregation + log_softmax
  agg_out_kernel<<<GRID_AO, 256, 0, stream>>>(yl8, yr, row_start, nbr, inv_deg, out);
}